// Round 11
// baseline (279.521 us; speedup 1.0000x reference)
//
#include <hip/hip_runtime.h>
#include <math.h>

#define NN 512
#define HD 64
#define EPSV 1e-5f

// ======================= multi-mode GEMM body ========================
// 64(M) x 64(N) tile, 256 threads, 4x4 micro-tile, BK=64, transposed-A LDS.
// A-fragment = one ds_read_b128 (4 rows), B-fragment = one ds_read_b128:
// 32 fma per 2 LDS reads (2x the fma/LDS-cycle of the old 32x64/2x4 tile).
// mode 0: plain A (M x K), row guard vs M
// mode 1: A = concat[A | A2] (256|256)
// mode 2: A = gather3: segs of 256 from A[row], A[nb0], A[nb1]; nb in-block
// mode 3: A = virtual Hc: [H1(256)|H2row(64,bcast)|H3(64)|h4col(1)], K=385
// mode 4: A[row][j] = adj[row][j] ? expwsc[j] : 0; row-sum fused, epilogue norm
struct GD {
  const float *A, *A2, *A3, *A4;
  const int* I;
  const float *B, *bias;
  float* C;
  int M, K, Nn, mode, act;
};

#define GEMM_SMEM (17408 + 17408 + 2304)
#define MEGA_SMEM 38656

__device__ __forceinline__ void gemm_body(char* smem, const GD& d, int bx, int by) {
  float (*At)[68] = (float (*)[68])smem;               // [k][row], 64x68
  float (*Bs)[68] = (float (*)[68])(smem + 17408);     // [k][col], 64x68
  char* extra = smem + 17408 + 17408;
  int* nbl = (int*)extra;                 // mode 2: 64 rows x {n0,n1,valid}
  float* wscl = (float*)extra;            // mode 4: exp(wsc) (512)
  float* rowsuml = wscl + 512;            // mode 4: 64

  const int t = threadIdx.x;
  const int tx = t & 15, ty = t >> 4;
  const int rowbase = by * 64, colbase = bx * 64;
  const int K = d.K, Nn = d.Nn, mode = d.mode, M = d.M;
  if (rowbase >= M) return;

  if (mode == 2) {
    int wave = t >> 6, lane = t & 63;
    for (int rr = wave; rr < 64; rr += 4) {
      int row = rowbase + rr;
      int n0 = -1, n1 = -1, cnt = 0;
      for (int c = 0; c < 8; ++c) {
        unsigned long long mm = __ballot(d.I[row * NN + c * 64 + lane] != 0);
        cnt += (int)__popcll(mm);
        if (n0 < 0 && mm) { n0 = c * 64 + (int)__builtin_ctzll(mm); mm &= mm - 1; }
        if (n1 < 0 && mm) { n1 = c * 64 + (int)__builtin_ctzll(mm); }
      }
      if (lane == 0) { nbl[rr * 3] = n0; nbl[rr * 3 + 1] = n1; nbl[rr * 3 + 2] = (cnt >= 2); }
    }
    __syncthreads();
  } else if (mode == 4) {
    wscl[t] = d.A2[t];
    wscl[256 + t] = d.A2[256 + t];
    __syncthreads();
  }

  float4 aR[4], bR[4];
  float rs[4] = {0.f, 0.f, 0.f, 0.f};  // mode-4 row sums, rows (t>>4)+16j

  auto loadA = [&](int k0) {
#pragma unroll
    for (int j = 0; j < 4; ++j) {
      int idx = t + j * 256;
      int r = idx >> 4, c0 = (idx & 15) * 4;
      int row = rowbase + r, gk = k0 + c0;
      float4 v4 = make_float4(0.f, 0.f, 0.f, 0.f);
      if (mode == 0) {
        if (row < M && gk < K) v4 = *(const float4*)&d.A[(size_t)row * K + gk];
      } else if (mode == 1) {
        if (gk < 256) v4 = *(const float4*)&d.A[row * 256 + gk];
        else v4 = *(const float4*)&d.A2[row * 256 + gk - 256];
      } else if (mode == 2) {
        int seg = gk >> 8;
        int src = (seg == 0) ? row : (nbl[r * 3 + 2] ? nbl[r * 3 + seg - 1] : -1);
        if (src >= 0) v4 = *(const float4*)&d.A[src * 256 + (gk & 255)];
      } else if (mode == 3) {
        if (gk + 3 < 256) v4 = *(const float4*)&d.A[row * 256 + gk];
        else if (gk >= 256 && gk + 3 < 320) v4 = *(const float4*)&d.A2[gk - 256];
        else if (gk >= 320 && gk + 3 < 384) v4 = *(const float4*)&d.A3[row * 64 + gk - 320];
        else if (gk == 384) v4.x = (row < 64) ? d.A4[row] : 0.f;
      } else {  // mode 4
        int4 a4 = *(const int4*)&d.I[row * NN + gk];
        v4.x = a4.x ? wscl[gk + 0] : 0.f;
        v4.y = a4.y ? wscl[gk + 1] : 0.f;
        v4.z = a4.z ? wscl[gk + 2] : 0.f;
        v4.w = a4.w ? wscl[gk + 3] : 0.f;
        rs[j] += v4.x + v4.y + v4.z + v4.w;
      }
      aR[j] = v4;
    }
  };
  auto loadB = [&](int k0) {
#pragma unroll
    for (int j = 0; j < 4; ++j) {
      int idx = t + j * 256;
      int r = idx >> 4, c0 = (idx & 15) * 4;
      int gk = k0 + r;
      float4 v4 = make_float4(0.f, 0.f, 0.f, 0.f);
      if (gk < K) v4 = *(const float4*)&d.B[(size_t)gk * Nn + colbase + c0];
      bR[j] = v4;
    }
  };
  auto stos = [&]() {
#pragma unroll
    for (int j = 0; j < 4; ++j) {
      int idx = t + j * 256;
      int r = idx >> 4, c0 = (idx & 15) * 4;
      At[c0 + 0][r] = aR[j].x;
      At[c0 + 1][r] = aR[j].y;
      At[c0 + 2][r] = aR[j].z;
      At[c0 + 3][r] = aR[j].w;
    }
#pragma unroll
    for (int j = 0; j < 4; ++j) {
      int idx = t + j * 256;
      int r = idx >> 4, c0 = (idx & 15) * 4;
      *(float4*)&Bs[r][c0] = bR[j];
    }
  };

  float4 acc[4];
#pragma unroll
  for (int i = 0; i < 4; ++i) acc[i] = make_float4(0.f, 0.f, 0.f, 0.f);

  int iters = (K + 63) >> 6;
  loadA(0); loadB(0);
  for (int it = 0; it < iters; ++it) {
    stos();
    __syncthreads();
    if (it + 1 < iters) { loadA((it + 1) << 6); loadB((it + 1) << 6); }
#pragma unroll 8
    for (int kk = 0; kk < 64; ++kk) {
      float4 av = *(const float4*)&At[kk][ty * 4];   // 4 rows, one b128
      float4 bv = *(const float4*)&Bs[kk][tx * 4];   // 4 cols, one b128
      acc[0].x += av.x * bv.x; acc[0].y += av.x * bv.y; acc[0].z += av.x * bv.z; acc[0].w += av.x * bv.w;
      acc[1].x += av.y * bv.x; acc[1].y += av.y * bv.y; acc[1].z += av.y * bv.z; acc[1].w += av.y * bv.w;
      acc[2].x += av.z * bv.x; acc[2].y += av.z * bv.y; acc[2].z += av.z * bv.z; acc[2].w += av.z * bv.w;
      acc[3].x += av.w * bv.x; acc[3].y += av.w * bv.y; acc[3].z += av.w * bv.z; acc[3].w += av.w * bv.w;
    }
    __syncthreads();
  }

  if (mode == 4) {
    // reduce rs[j] across the 16 threads (tx) sharing row (t>>4)+16j
#pragma unroll
    for (int off = 8; off; off >>= 1) {
#pragma unroll
      for (int j = 0; j < 4; ++j) rs[j] += __shfl_xor(rs[j], off, 16);
    }
    if (tx == 0) {
#pragma unroll
      for (int j = 0; j < 4; ++j) rowsuml[ty + j * 16] = rs[j];
    }
    __syncthreads();
  }

  int col = colbase + tx * 4;
  float4 bv = make_float4(0.f, 0.f, 0.f, 0.f);
  if (d.bias) bv = *(const float4*)&d.bias[col];
#pragma unroll
  for (int i = 0; i < 4; ++i) {
    int row = rowbase + ty * 4 + i;
    if (row >= M) break;
    float4 o;
    o.x = acc[i].x + bv.x; o.y = acc[i].y + bv.y; o.z = acc[i].z + bv.z; o.w = acc[i].w + bv.w;
    if (d.act) {
      o.x = fmaxf(o.x, 0.f); o.y = fmaxf(o.y, 0.f);
      o.z = fmaxf(o.z, 0.f); o.w = fmaxf(o.w, 0.f);
    }
    if (mode == 4) {
      float s = 1.f / rowsuml[ty * 4 + i];
      o.x *= s; o.y *= s; o.z *= s; o.w *= s;
    }
    *(float4*)&d.C[(size_t)row * Nn + col] = o;
  }
}

// expwsc[j] = exp(V[j] . u), u = W1 @ a_std1   [wsc = V@(W1@a_std1)]
__device__ void wsc_body(char* smem, const float* W1, const float* a_std1,
                         const float* V, float* expwsc, int grp) {
  float* asl = (float*)smem;       // 256
  float* ul  = asl + 256;          // 256
  int t = threadIdx.x;
  asl[t] = a_std1[t];
  __syncthreads();
  {
    float s = 0.f;
    const float* wr = W1 + t * 256;
    for (int h = 0; h < 256; h += 4) {
      float4 w4 = *(const float4*)&wr[h];
      float4 a4 = *(const float4*)&asl[h];
      s += w4.x * a4.x + w4.y * a4.y + w4.z * a4.z + w4.w * a4.w;
    }
    ul[t] = s;
  }
  __syncthreads();
  int wave = t >> 6, lane = t & 63;
  float4 u4 = *(const float4*)&ul[lane * 4];
  int j0 = grp * 128;
  for (int j = j0 + wave; j < j0 + 128; j += 4) {
    float4 v4 = *(const float4*)&V[j * 256 + lane * 4];
    float s = v4.x * u4.x + v4.y * u4.y + v4.z * u4.z + v4.w * u4.w;
#pragma unroll
    for (int off = 32; off; off >>= 1) s += __shfl_xor(s, off, 64);
    if (lane == 0) expwsc[j] = __expf(s);
  }
}

// launch 1: z heaviest-first (K=768 gather, K=512 concat lead); grid 4x8x7
struct GD7 { GD d[7]; };
__global__ __launch_bounds__(256) void gemm7_k(GD7 ds) {
  __shared__ __align__(16) char smem[GEMM_SMEM];
  int z = blockIdx.z;
  if (z == 6) {
    if (blockIdx.y != 0) return;        // 4 blocks: bx = row-group
    wsc_body(smem, ds.d[6].A, ds.d[6].A2, ds.d[6].A3, ds.d[6].C, blockIdx.x);
    return;
  }
  gemm_body(smem, ds.d[z], blockIdx.x, blockIdx.y);
}
__global__ __launch_bounds__(256) void gemm1_k(GD d) {
  __shared__ __align__(16) char smem[GEMM_SMEM];
  gemm_body(smem, d, blockIdx.x, blockIdx.y);
}

// ============================ pair body =================================
__device__ void pair_body(char* smem,
    const float* __restrict__ P, const float* __restrict__ Q,
    const float* __restrict__ b1, const float* __restrict__ ce_w2,
    const float* __restrict__ a_c0, const float* __restrict__ a_c1,
    float* __restrict__ mpart, float* __restrict__ dpart,
    float* __restrict__ spart, int byy, int bxx) {
  float* Pl  = (float*)smem;        // 16*260, P + b1 folded
  float* Ql  = Pl + 16 * 260;       // 16*260
  float* el  = Ql + 16 * 260;       // 16*20
  float* wcl = el + 16 * 20;        // 256
  float* red = wcl + 256;           // 256
  float* sk  = red + 256;           // 256
  float* sbl = sk + 256;            // 256
  int t = threadIdx.x;

  if (t < 64) red[t] = a_c0[t] + a_c1[t];
  __syncthreads();
  {
    float s = 0.f;
    const float* w2r = ce_w2 + t * 64;
#pragma unroll 8
    for (int h = 0; h < 64; ++h) s += w2r[h] * red[h];
    wcl[t] = s;
  }
  int i0 = byy * 16, j0 = bxx * 16;
  for (int e = t; e < 1024; e += 256) {
    int r = e >> 6, c4 = (e & 63) * 4;
    float4 bb = *(const float4*)&b1[c4];
    float4 pv = *(const float4*)&P[(i0 + r) * 256 + c4];
    pv.x += bb.x; pv.y += bb.y; pv.z += bb.z; pv.w += bb.w;
    *(float4*)&Pl[r * 260 + c4] = pv;
    *(float4*)&Ql[r * 260 + c4] = *(const float4*)&Q[(j0 + r) * 256 + c4];
  }
  __syncthreads();

  int a = t >> 4, b = t & 15;
  const float* pr = &Pl[a * 260];
  const float* qr = &Ql[b * 260];
  float4 c4a = make_float4(0.f, 0.f, 0.f, 0.f);
#pragma unroll 8
  for (int k4 = 0; k4 < 64; ++k4) {
    float4 w = *(const float4*)&wcl[k4 * 4];
    float4 p = *(const float4*)&pr[k4 * 4];
    float4 q = *(const float4*)&qr[k4 * 4];
    c4a.x += fmaxf(p.x + q.x, 0.f) * w.x;
    c4a.y += fmaxf(p.y + q.y, 0.f) * w.y;
    c4a.z += fmaxf(p.z + q.z, 0.f) * w.z;
    c4a.w += fmaxf(p.w + q.w, 0.f) * w.w;
  }
  float s = c4a.x + c4a.y + c4a.z + c4a.w;
  if (i0 + a == j0 + b) s = -INFINITY;
  red[t] = s; __syncthreads();
  for (int ss = 128; ss; ss >>= 1) { if (t < ss) red[t] = fmaxf(red[t], red[t + ss]); __syncthreads(); }
  float mb = red[0];
  __syncthreads();
  float e = __expf(s - mb);
  el[a * 20 + b] = e;
  red[t] = e; __syncthreads();
  for (int ss = 128; ss; ss >>= 1) { if (t < ss) red[t] += red[t + ss]; __syncthreads(); }
  float db = red[0];
  __syncthreads();

  // pass 2: thread t owns feature k=t (static register indexing ONLY —
  // runtime-indexed register arrays demote to scratch/HBM: R4's 339us bug)
  float qv[16];
#pragma unroll
  for (int j = 0; j < 16; ++j) qv[j] = Ql[j * 260 + t];
  float rk = 0.f;
#pragma unroll 4
  for (int i = 0; i < 16; ++i) {
    float pv = Pl[i * 260 + t];
    const float* erow = &el[i * 20];
#pragma unroll
    for (int j4 = 0; j4 < 4; ++j4) {
      float4 e4 = *(const float4*)&erow[j4 * 4];
      rk += e4.x * fmaxf(pv + qv[j4 * 4 + 0], 0.f);
      rk += e4.y * fmaxf(pv + qv[j4 * 4 + 1], 0.f);
      rk += e4.z * fmaxf(pv + qv[j4 * 4 + 2], 0.f);
      rk += e4.w * fmaxf(pv + qv[j4 * 4 + 3], 0.f);
    }
  }
  sk[t] = rk;
  __syncthreads();
  {
    int h = t & 63, q = t >> 6;
    float s2 = 0.f;
    for (int k = q * 64; k < q * 64 + 64; ++k) s2 += sk[k] * ce_w2[k * 64 + h];
    sbl[q * 64 + h] = s2;
  }
  __syncthreads();
  int blk = byy * 32 + bxx;
  if (t < 64) spart[blk * 64 + t] = sbl[t] + sbl[64 + t] + sbl[128 + t] + sbl[192 + t];
  if (t == 0) { mpart[blk] = mb; dpart[blk] = db; }
}

// ============================== mega kernel ===============================
// 1072 blocks, ONE job each: 0..31 H1 gemm (4x8), 32..39 tf, 40..47 cf4,
// 48..1071 pair 16x16 tiles
struct MegaArgs {
  const float *P, *Q, *b1, *ce_w2, *a_c0, *a_c1;
  float *mpart, *dpart, *spart;
  GD gH1, gTf, gCf;
};

__global__ __launch_bounds__(256) void mega_k(MegaArgs a) {
  __shared__ __align__(16) char smem[MEGA_SMEM];
  int b = blockIdx.x;
  if (b < 32) {
    gemm_body(smem, a.gH1, b & 3, b >> 2);
  } else if (b < 40) {
    gemm_body(smem, a.gTf, 0, b - 32);
  } else if (b < 48) {
    gemm_body(smem, a.gCf, 0, b - 40);
  } else {
    int p = b - 48;
    pair_body(smem, a.P, a.Q, a.b1, a.ce_w2, a.a_c0, a.a_c1,
              a.mpart, a.dpart, a.spart, p >> 5, p & 31);
  }
}

// ======================= mini kernel (3 blocks x 256) ====================
// block 0: H2 finalize   block 1: h3 prefix mean   block 2: colsum
__global__ __launch_bounds__(256) void mini_k(
    const float* __restrict__ mpart, const float* __restrict__ dpart,
    const float* __restrict__ spart, const float* __restrict__ ce_b2,
    float* __restrict__ H2row,
    const float* __restrict__ tf, float* __restrict__ H3,
    const float* __restrict__ cf4, float* __restrict__ h4vec) {
  __shared__ float eb[1024];
  __shared__ float red[256];
  int b = blockIdx.x, t = threadIdx.x;
  if (b == 0) {
    float m = -INFINITY;
#pragma unroll
    for (int c = 0; c < 4; ++c) m = fmaxf(m, mpart[c * 256 + t]);
    red[t] = m; __syncthreads();
    for (int s = 128; s; s >>= 1) { if (t < s) red[t] = fmaxf(red[t], red[t + s]); __syncthreads(); }
    float M = red[0]; __syncthreads();
    float dsum = 0.f;
#pragma unroll
    for (int c = 0; c < 4; ++c) {
      float e = __expf(mpart[c * 256 + t] - M);
      eb[c * 256 + t] = e;
      dsum += e * dpart[c * 256 + t];
    }
    red[t] = dsum; __syncthreads();
    for (int s = 128; s; s >>= 1) { if (t < s) red[t] += red[t + s]; __syncthreads(); }
    float D = red[0]; __syncthreads();
    int h = t & 63, g = t >> 6;
    float s2 = 0.f;
    for (int b2 = g * 256; b2 < g * 256 + 256; ++b2) s2 += eb[b2] * spart[b2 * 64 + h];
    red[t] = s2; __syncthreads();
    for (int p = 2; p; p >>= 1) { if (g < p) red[g * 64 + h] += red[(g + p) * 64 + h]; __syncthreads(); }
    if (t < 64) H2row[t] = red[t] / D + ce_b2[t];
  } else if (b == 1) {
    // H3[i] = mean(tf[0..i]) — ts broadcast makes causal softmax uniform (R1)
    int h = t & 63, g = t >> 6;
    float run = 0.f;
    for (int r = 0; r < 128; ++r) run += tf[((g << 7) + r) * 64 + h];
    eb[g * 64 + h] = run;
    __syncthreads();
    float off = 0.f;
    for (int gg = 0; gg < g; ++gg) off += eb[gg * 64 + h];
    run = off;
    for (int r = 0; r < 128; ++r) {
      int i = (g << 7) + r;
      run += tf[i * 64 + h];
      H3[i * 64 + h] = run / (float)(i + 1);
    }
  } else {
    int h = t & 63, g = t >> 6;
    float s = 0.f;
    for (int r = 0; r < 128; ++r) s += cf4[((g << 7) + r) * 64 + h];
    red[t] = s; __syncthreads();
    for (int p = 2; p; p >>= 1) { if (g < p) red[g * 64 + h] += red[(g + p) * 64 + h]; __syncthreads(); }
    if (t < 64) h4vec[t] = red[t];
  }
}

// ---------------- layernorm + elu ----------------
__global__ void ln_elu_kernel(const float* __restrict__ X, const float* __restrict__ g,
                              const float* __restrict__ b, float* __restrict__ out) {
  __shared__ float red[256];
  int i = blockIdx.x, tid = threadIdx.x;
  float x = X[i * 256 + tid];
  red[tid] = x; __syncthreads();
  for (int s = 128; s; s >>= 1) { if (tid < s) red[tid] += red[tid + s]; __syncthreads(); }
  float mu = red[0] * (1.f / 256.f);
  __syncthreads();
  float d = x - mu;
  red[tid] = d * d; __syncthreads();
  for (int s = 128; s; s >>= 1) { if (tid < s) red[tid] += red[tid + s]; __syncthreads(); }
  float var = red[0] * (1.f / 256.f);
  float y = d / sqrtf(var + EPSV) * g[tid] + b[tid];
  out[i * 256 + tid] = (y > 0.f) ? y : (expf(y) - 1.f);
}

static GD mkgd(const float* A, const float* A2, const float* A3, const float* A4,
               const int* I, const float* B, const float* bias, float* C,
               int M, int K, int Nn, int mode, int act) {
  GD g{A, A2, A3, A4, I, B, bias, C, M, K, Nn, mode, act};
  return g;
}

extern "C" void kernel_launch(void* const* d_in, const int* in_sizes, int n_in,
                              void* d_out, int out_size, void* d_ws, size_t ws_size,
                              hipStream_t stream) {
  const float* V      = (const float*)d_in[0];
  const int*   adj    = (const int*)  d_in[1];
  const float* ph     = (const float*)d_in[2];
  const float* W1     = (const float*)d_in[3];
  // d_in[4] = a_std0: cancels in row softmax — unused
  const float* a_std1 = (const float*)d_in[5];
  const float* ce_w1  = (const float*)d_in[6];
  const float* ce_b1  = (const float*)d_in[7];
  const float* ce_w2  = (const float*)d_in[8];
  const float* ce_b2  = (const float*)d_in[9];
  const float* a_c0   = (const float*)d_in[10];
  const float* a_c1   = (const float*)d_in[11];
  const float* te_w1  = (const float*)d_in[12];
  const float* te_b1  = (const float*)d_in[13];
  const float* te_w2  = (const float*)d_in[14];
  const float* te_b2  = (const float*)d_in[15];
  // d_in[16..17] = a_t0,a_t1: dead (uniform causal softmax)
  const float* co_w1  = (const float*)d_in[18];
  const float* co_b1  = (const float*)d_in[19];
  const float* co_w2  = (const float*)d_in[20];
  const float* co_b2  = (const float*)d_in[21];
  // d_in[22..23] = a_co0,a_co1: size-1 softmax == 1 — unused
  const float* W2     = (const float*)d_in[24];
  const float* Wo     = (const float*)d_in[25];
  const float* bo     = (const float*)d_in[26];
  const float* ln_g   = (const float*)d_in[27];
  const float* ln_b   = (const float*)d_in[28];
  float* out = (float*)d_out;

  float* ws = (float*)d_ws;
  size_t off = 0;
  auto alloc = [&](size_t n) { float* p = ws + off; off += (n + 15) & ~(size_t)15; return p; };

  float* Wh1    = alloc(512 * 256);
  float* Pb     = alloc(512 * 256);
  float* Qb     = alloc(512 * 256);
  float* tfh    = alloc(512 * 256);
  float* cf4h   = alloc(512 * 256);
  float* H1     = alloc(512 * 256);
  float* Wfused = alloc(385 * 256);
  float* T2     = alloc(512 * 256);
  float* tf     = alloc(512 * 64);
  float* cf4    = alloc(512 * 64);
  float* H3     = alloc(512 * 64);
  float* spart  = alloc(1024 * 64);
  float* mpart  = alloc(1024);
  float* dpart  = alloc(1024);
  float* expwsc = alloc(512);
  float* H2row  = alloc(64);
  float* h4vec  = alloc(64);
  (void)ws_size; (void)in_sizes; (void)n_in; (void)out_size;

  // ---- launch 1: six leading GEMMs + wsc (z heaviest-first) ----
  GD7 sA;
  sA.d[0] = mkgd(V, 0, 0, 0, adj, co_w1, co_b1, cf4h, 512, 768, 256, 2, 1);  // K=768
  sA.d[1] = mkgd(V, ph, 0, 0, 0, te_w1, te_b1, tfh, 512, 512, 256, 1, 1);    // K=512
  sA.d[2] = mkgd(V, 0, 0, 0, 0, W1, 0, Wh1, 512, 256, 256, 0, 0);
  sA.d[3] = mkgd(V, 0, 0, 0, 0, ce_w1, 0, Pb, 512, 256, 256, 0, 0);
  sA.d[4] = mkgd(V, 0, 0, 0, 0, ce_w1 + 256 * 256, 0, Qb, 512, 256, 256, 0, 0);
  sA.d[5] = mkgd(W2, 0, 0, 0, 0, Wo, 0, Wfused, 385, 256, 256, 0, 0);
  sA.d[6] = mkgd(W1, a_std1, V, 0, 0, 0, 0, expwsc, 512, 256, 1, 6, 0);
  gemm7_k<<<dim3(4, 8, 7), 256, 0, stream>>>(sA);

  // ---- launch 2: 1072 blocks, one job each ----
  MegaArgs ma;
  ma.P = Pb; ma.Q = Qb; ma.b1 = ce_b1; ma.ce_w2 = ce_w2;
  ma.a_c0 = a_c0; ma.a_c1 = a_c1;
  ma.mpart = mpart; ma.dpart = dpart; ma.spart = spart;
  ma.gH1 = mkgd(0, expwsc, 0, 0, adj, Wh1, 0, H1, 512, 512, 256, 4, 0);
  ma.gTf = mkgd(tfh, 0, 0, 0, 0, te_w2, te_b2, tf, 512, 256, 64, 0, 0);
  ma.gCf = mkgd(cf4h, 0, 0, 0, 0, co_w2, co_b2, cf4, 512, 256, 64, 0, 0);
  mega_k<<<1072, 256, 0, stream>>>(ma);

  // ---- launch 3: H2 finalize + h3 prefix mean + colsum ----
  mini_k<<<3, 256, 0, stream>>>(mpart, dpart, spart, ce_b2, H2row, tf, H3, cf4, h4vec);

  // ---- launch 4: T2 = virtual-Hc @ Wfused + bo ----
  GD gF = mkgd(H1, H2row, H3, h4vec, 0, Wfused, bo, T2, 512, 385, 256, 3, 0);
  gemm1_k<<<dim3(4, 8), 256, 0, stream>>>(gF);

  // ---- launch 5: layernorm + elu ----
  ln_elu_kernel<<<512, 256, 0, stream>>>(T2, ln_g, ln_b, out);
}

// Round 12
// 201.710 us; speedup vs baseline: 1.3858x; 1.3858x over previous
//
#include <hip/hip_runtime.h>
#include <math.h>

#define NN 512
#define HD 64
#define EPSV 1e-5f

// ======================= multi-mode pipelined GEMM ========================
// 32(M) x 64(N) tile, 256 threads, 2x4 micro-tile, BK=64, transposed-A LDS.
// (R11 post-mortem: 64x64/4x4 regressed — stride-68 A-store is 8-way bank
//  conflicted and 224 blocks < 256 CUs starves TLP. This 32-row shape at
//  448/1120 blocks is the measured local optimum.)
struct GD {
  const float *A, *A2, *A3, *A4;
  const int* I;
  const float *B, *bias;
  float* C;
  int M, K, Nn, mode, act;
};

#define GEMM_SMEM (8704 + 17408 + 2176)
#define MEGA_SMEM 38656

__device__ __forceinline__ void gemm_body(char* smem, const GD& d, int bx, int by) {
  float (*At)[34] = (float (*)[34])smem;              // [k][row], 64x34
  float (*Bs)[68] = (float (*)[68])(smem + 8704);     // [k][col], 64x68
  char* extra = smem + 8704 + 17408;
  int* nbl = (int*)extra;                 // mode 2: 32 rows x {n0,n1,valid}
  float* wscl = (float*)extra;            // mode 4: exp(wsc) (512)
  float* rowsuml = wscl + 512;            // mode 4: 32

  const int t = threadIdx.x;
  const int tx = t & 15, ty = t >> 4;
  const int rowbase = by * 32, colbase = bx * 64;
  const int K = d.K, Nn = d.Nn, mode = d.mode, M = d.M;
  if (rowbase >= M) return;

  if (mode == 2) {
    int wave = t >> 6, lane = t & 63;
    for (int rr = wave; rr < 32; rr += 4) {
      int row = rowbase + rr;
      int n0 = -1, n1 = -1, cnt = 0;
      for (int c = 0; c < 8; ++c) {
        unsigned long long mm = __ballot(d.I[row * NN + c * 64 + lane] != 0);
        cnt += (int)__popcll(mm);
        if (n0 < 0 && mm) { n0 = c * 64 + (int)__builtin_ctzll(mm); mm &= mm - 1; }
        if (n1 < 0 && mm) { n1 = c * 64 + (int)__builtin_ctzll(mm); }
      }
      if (lane == 0) { nbl[rr * 3] = n0; nbl[rr * 3 + 1] = n1; nbl[rr * 3 + 2] = (cnt >= 2); }
    }
    __syncthreads();
  } else if (mode == 4) {
    wscl[t] = d.A2[t];
    wscl[256 + t] = d.A2[256 + t];
    __syncthreads();
  }

  float4 aR[2], bR[4];
  float rs0 = 0.f, rs1 = 0.f;   // mode-4 row sums (rows t>>4 and 16+(t>>4))

  auto loadA = [&](int k0) {
#pragma unroll
    for (int j = 0; j < 2; ++j) {
      int idx = t + j * 256;
      int r = idx >> 4, c0 = (idx & 15) * 4;
      int row = rowbase + r, gk = k0 + c0;
      float4 v4 = make_float4(0.f, 0.f, 0.f, 0.f);
      if (mode == 0) {
        if (row < M && gk < K) v4 = *(const float4*)&d.A[(size_t)row * K + gk];
      } else if (mode == 1) {
        if (gk < 256) v4 = *(const float4*)&d.A[row * 256 + gk];
        else v4 = *(const float4*)&d.A2[row * 256 + gk - 256];
      } else if (mode == 2) {
        int seg = gk >> 8;
        int src = (seg == 0) ? row : (nbl[r * 3 + 2] ? nbl[r * 3 + seg - 1] : -1);
        if (src >= 0) v4 = *(const float4*)&d.A[src * 256 + (gk & 255)];
      } else if (mode == 3) {
        if (gk + 3 < 256) v4 = *(const float4*)&d.A[row * 256 + gk];
        else if (gk >= 256 && gk + 3 < 320) v4 = *(const float4*)&d.A2[gk - 256];
        else if (gk >= 320 && gk + 3 < 384) v4 = *(const float4*)&d.A3[row * 64 + gk - 320];
        else if (gk == 384) v4.x = (row < 64) ? d.A4[row] : 0.f;
      } else {  // mode 4
        int4 a4 = *(const int4*)&d.I[row * NN + gk];
        v4.x = a4.x ? wscl[gk + 0] : 0.f;
        v4.y = a4.y ? wscl[gk + 1] : 0.f;
        v4.z = a4.z ? wscl[gk + 2] : 0.f;
        v4.w = a4.w ? wscl[gk + 3] : 0.f;
        float ss = v4.x + v4.y + v4.z + v4.w;
        if (j == 0) rs0 += ss; else rs1 += ss;
      }
      aR[j] = v4;
    }
  };
  auto loadB = [&](int k0) {
#pragma unroll
    for (int j = 0; j < 4; ++j) {
      int idx = t + j * 256;
      int r = idx >> 4, c0 = (idx & 15) * 4;
      int gk = k0 + r;
      float4 v4 = make_float4(0.f, 0.f, 0.f, 0.f);
      if (gk < K) v4 = *(const float4*)&d.B[(size_t)gk * Nn + colbase + c0];
      bR[j] = v4;
    }
  };
  auto stos = [&]() {
#pragma unroll
    for (int j = 0; j < 2; ++j) {
      int idx = t + j * 256;
      int r = idx >> 4, c0 = (idx & 15) * 4;
      At[c0 + 0][r] = aR[j].x;
      At[c0 + 1][r] = aR[j].y;
      At[c0 + 2][r] = aR[j].z;
      At[c0 + 3][r] = aR[j].w;
    }
#pragma unroll
    for (int j = 0; j < 4; ++j) {
      int idx = t + j * 256;
      int r = idx >> 4, c0 = (idx & 15) * 4;
      *(float4*)&Bs[r][c0] = bR[j];
    }
  };

  float4 acc0 = make_float4(0.f, 0.f, 0.f, 0.f);
  float4 acc1 = make_float4(0.f, 0.f, 0.f, 0.f);

  int iters = (K + 63) >> 6;
  loadA(0); loadB(0);
  for (int it = 0; it < iters; ++it) {
    stos();
    __syncthreads();
    if (it + 1 < iters) { loadA((it + 1) << 6); loadB((it + 1) << 6); }
#pragma unroll 8
    for (int kk = 0; kk < 64; ++kk) {
      float2 a = *(const float2*)&At[kk][ty * 2];
      float4 b = *(const float4*)&Bs[kk][tx * 4];
      acc0.x += a.x * b.x; acc0.y += a.x * b.y; acc0.z += a.x * b.z; acc0.w += a.x * b.w;
      acc1.x += a.y * b.x; acc1.y += a.y * b.y; acc1.z += a.y * b.z; acc1.w += a.y * b.w;
    }
    __syncthreads();
  }

  if (mode == 4) {
    float a0 = rs0, a1 = rs1;
#pragma unroll
    for (int off = 8; off; off >>= 1) {
      a0 += __shfl_xor(a0, off, 16);
      a1 += __shfl_xor(a1, off, 16);
    }
    if ((t & 15) == 0) { rowsuml[t >> 4] = a0; rowsuml[16 + (t >> 4)] = a1; }
    __syncthreads();
  }

  int col = colbase + tx * 4;
  float4 bv = make_float4(0.f, 0.f, 0.f, 0.f);
  if (d.bias) bv = *(const float4*)&d.bias[col];
  int row0 = rowbase + ty * 2;
  float4 o0, o1;
  o0.x = acc0.x + bv.x; o0.y = acc0.y + bv.y; o0.z = acc0.z + bv.z; o0.w = acc0.w + bv.w;
  o1.x = acc1.x + bv.x; o1.y = acc1.y + bv.y; o1.z = acc1.z + bv.z; o1.w = acc1.w + bv.w;
  if (d.act) {
    o0.x = fmaxf(o0.x, 0.f); o0.y = fmaxf(o0.y, 0.f); o0.z = fmaxf(o0.z, 0.f); o0.w = fmaxf(o0.w, 0.f);
    o1.x = fmaxf(o1.x, 0.f); o1.y = fmaxf(o1.y, 0.f); o1.z = fmaxf(o1.z, 0.f); o1.w = fmaxf(o1.w, 0.f);
  }
  if (mode == 4) {
    float s0 = 1.f / rowsuml[ty * 2], s1 = 1.f / rowsuml[ty * 2 + 1];
    o0.x *= s0; o0.y *= s0; o0.z *= s0; o0.w *= s0;
    o1.x *= s1; o1.y *= s1; o1.z *= s1; o1.w *= s1;
  }
  if (row0 < M)     *(float4*)&d.C[(size_t)row0 * Nn + col] = o0;
  if (row0 + 1 < M) *(float4*)&d.C[(size_t)(row0 + 1) * Nn + col] = o1;
}

// expwsc[j] = exp(V[j] . u), u = W1 @ a_std1   [wsc = V@(W1@a_std1)]
__device__ void wsc_body(char* smem, const float* W1, const float* a_std1,
                         const float* V, float* expwsc, int grp) {
  float* asl = (float*)smem;       // 256
  float* ul  = asl + 256;          // 256
  int t = threadIdx.x;
  asl[t] = a_std1[t];
  __syncthreads();
  {
    float s = 0.f;
    const float* wr = W1 + t * 256;
    for (int h = 0; h < 256; h += 4) {
      float4 w4 = *(const float4*)&wr[h];
      float4 a4 = *(const float4*)&asl[h];
      s += w4.x * a4.x + w4.y * a4.y + w4.z * a4.z + w4.w * a4.w;
    }
    ul[t] = s;
  }
  __syncthreads();
  int wave = t >> 6, lane = t & 63;
  float4 u4 = *(const float4*)&ul[lane * 4];
  int j0 = grp * 128;
  for (int j = j0 + wave; j < j0 + 128; j += 4) {
    float4 v4 = *(const float4*)&V[j * 256 + lane * 4];
    float s = v4.x * u4.x + v4.y * u4.y + v4.z * u4.z + v4.w * u4.w;
#pragma unroll
    for (int off = 32; off; off >>= 1) s += __shfl_xor(s, off, 64);
    if (lane == 0) expwsc[j] = __expf(s);
  }
}

struct GD7 { GD d[7]; };
__global__ __launch_bounds__(256) void gemm7_k(GD7 ds) {
  __shared__ __align__(16) char smem[GEMM_SMEM];
  int z = blockIdx.z;
  if (z == 6) {
    if (blockIdx.y != 0) return;        // 4 blocks: bx = row-group
    wsc_body(smem, ds.d[6].A, ds.d[6].A2, ds.d[6].A3, ds.d[6].C, blockIdx.x);
    return;
  }
  gemm_body(smem, ds.d[z], blockIdx.x, blockIdx.y);
}
__global__ __launch_bounds__(256) void gemm1_k(GD d) {
  __shared__ __align__(16) char smem[GEMM_SMEM];
  gemm_body(smem, d, blockIdx.x, blockIdx.y);
}

// ============================ pair body =================================
__device__ void pair_body(char* smem,
    const float* __restrict__ P, const float* __restrict__ Q,
    const float* __restrict__ b1, const float* __restrict__ ce_w2,
    const float* __restrict__ a_c0, const float* __restrict__ a_c1,
    float* __restrict__ mpart, float* __restrict__ dpart,
    float* __restrict__ spart, int byy, int bxx) {
  float* Pl  = (float*)smem;        // 16*260, P + b1 folded
  float* Ql  = Pl + 16 * 260;       // 16*260
  float* el  = Ql + 16 * 260;       // 16*20
  float* wcl = el + 16 * 20;        // 256
  float* red = wcl + 256;           // 256
  float* sk  = red + 256;           // 256
  float* sbl = sk + 256;            // 256
  int t = threadIdx.x;

  if (t < 64) red[t] = a_c0[t] + a_c1[t];
  __syncthreads();
  {
    float s = 0.f;
    const float* w2r = ce_w2 + t * 64;
#pragma unroll 8
    for (int h = 0; h < 64; ++h) s += w2r[h] * red[h];
    wcl[t] = s;
  }
  int i0 = byy * 16, j0 = bxx * 16;
  for (int e = t; e < 1024; e += 256) {
    int r = e >> 6, c4 = (e & 63) * 4;
    float4 bb = *(const float4*)&b1[c4];
    float4 pv = *(const float4*)&P[(i0 + r) * 256 + c4];
    pv.x += bb.x; pv.y += bb.y; pv.z += bb.z; pv.w += bb.w;
    *(float4*)&Pl[r * 260 + c4] = pv;
    *(float4*)&Ql[r * 260 + c4] = *(const float4*)&Q[(j0 + r) * 256 + c4];
  }
  __syncthreads();

  int a = t >> 4, b = t & 15;
  const float* pr = &Pl[a * 260];
  const float* qr = &Ql[b * 260];
  float4 c4a = make_float4(0.f, 0.f, 0.f, 0.f);
#pragma unroll 8
  for (int k4 = 0; k4 < 64; ++k4) {
    float4 w = *(const float4*)&wcl[k4 * 4];
    float4 p = *(const float4*)&pr[k4 * 4];
    float4 q = *(const float4*)&qr[k4 * 4];
    c4a.x += fmaxf(p.x + q.x, 0.f) * w.x;
    c4a.y += fmaxf(p.y + q.y, 0.f) * w.y;
    c4a.z += fmaxf(p.z + q.z, 0.f) * w.z;
    c4a.w += fmaxf(p.w + q.w, 0.f) * w.w;
  }
  float s = c4a.x + c4a.y + c4a.z + c4a.w;
  if (i0 + a == j0 + b) s = -INFINITY;
  red[t] = s; __syncthreads();
  for (int ss = 128; ss; ss >>= 1) { if (t < ss) red[t] = fmaxf(red[t], red[t + ss]); __syncthreads(); }
  float mb = red[0];
  __syncthreads();
  float e = __expf(s - mb);
  el[a * 20 + b] = e;
  red[t] = e; __syncthreads();
  for (int ss = 128; ss; ss >>= 1) { if (t < ss) red[t] += red[t + ss]; __syncthreads(); }
  float db = red[0];
  __syncthreads();

  // pass 2: thread t owns feature k=t (static register indexing ONLY —
  // runtime-indexed register arrays demote to scratch/HBM: R4's 339us bug)
  float qv[16];
#pragma unroll
  for (int j = 0; j < 16; ++j) qv[j] = Ql[j * 260 + t];
  float rk = 0.f;
#pragma unroll 4
  for (int i = 0; i < 16; ++i) {
    float pv = Pl[i * 260 + t];
    const float* erow = &el[i * 20];
#pragma unroll
    for (int j4 = 0; j4 < 4; ++j4) {
      float4 e4 = *(const float4*)&erow[j4 * 4];
      rk += e4.x * fmaxf(pv + qv[j4 * 4 + 0], 0.f);
      rk += e4.y * fmaxf(pv + qv[j4 * 4 + 1], 0.f);
      rk += e4.z * fmaxf(pv + qv[j4 * 4 + 2], 0.f);
      rk += e4.w * fmaxf(pv + qv[j4 * 4 + 3], 0.f);
    }
  }
  sk[t] = rk;
  __syncthreads();
  {
    int h = t & 63, q = t >> 6;
    float s2 = 0.f;
    for (int k = q * 64; k < q * 64 + 64; ++k) s2 += sk[k] * ce_w2[k * 64 + h];
    sbl[q * 64 + h] = s2;
  }
  __syncthreads();
  int blk = byy * 32 + bxx;
  if (t < 64) spart[blk * 64 + t] = sbl[t] + sbl[64 + t] + sbl[128 + t] + sbl[192 + t];
  if (t == 0) { mpart[blk] = mb; dpart[blk] = db; }
}

// ============================== mega kernel ===============================
// 1120 blocks, ONE job each: 0..63 H1 gemm, 64..79 tf, 80..95 cf4,
// 96..1119 pair 16x16 tiles
struct MegaArgs {
  const float *P, *Q, *b1, *ce_w2, *a_c0, *a_c1;
  float *mpart, *dpart, *spart;
  GD gH1, gTf, gCf;
};

__global__ __launch_bounds__(256) void mega_k(MegaArgs a) {
  __shared__ __align__(16) char smem[MEGA_SMEM];
  int b = blockIdx.x;
  if (b < 64) {
    gemm_body(smem, a.gH1, b & 3, b >> 2);
  } else if (b < 80) {
    gemm_body(smem, a.gTf, 0, b - 64);
  } else if (b < 96) {
    gemm_body(smem, a.gCf, 0, b - 80);
  } else {
    int p = b - 96;
    pair_body(smem, a.P, a.Q, a.b1, a.ce_w2, a.a_c0, a.a_c1,
              a.mpart, a.dpart, a.spart, p >> 5, p & 31);
  }
}

// ======================= mini kernel (3 blocks x 1024) ====================
// block 0: H2 finalize (global max over 1024 tiles, D, H2row)
// block 1: h3 prefix mean     block 2: colsum -> h4vec
__global__ __launch_bounds__(1024) void mini_k(
    const float* __restrict__ mpart, const float* __restrict__ dpart,
    const float* __restrict__ spart, const float* __restrict__ ce_b2,
    float* __restrict__ H2row,
    const float* __restrict__ tf, float* __restrict__ H3,
    const float* __restrict__ cf4, float* __restrict__ h4vec) {
  __shared__ float A[1024];
  __shared__ float Bsh[1024];
  __shared__ float segsum[16][65];
  int b = blockIdx.x, t = threadIdx.x;
  if (b == 0) {
    float mv = mpart[t];
    A[t] = mv; __syncthreads();
    for (int s = 512; s; s >>= 1) { if (t < s) A[t] = fmaxf(A[t], A[t + s]); __syncthreads(); }
    float M = A[0];
    __syncthreads();
    float e = __expf(mv - M);
    Bsh[t] = e;
    A[t] = e * dpart[t];
    __syncthreads();
    for (int s = 512; s; s >>= 1) { if (t < s) A[t] += A[t + s]; __syncthreads(); }
    float D = A[0];
    __syncthreads();
    int h = t & 63, g = t >> 6;
    float s2 = 0.f;
    for (int b2 = g * 64; b2 < g * 64 + 64; ++b2) s2 += Bsh[b2] * spart[b2 * 64 + h];
    A[t] = s2;
    __syncthreads();
    for (int p = 8; p; p >>= 1) { if (g < p) A[g * 64 + h] += A[(g + p) * 64 + h]; __syncthreads(); }
    if (t < 64) H2row[t] = A[t] / D + ce_b2[t];
  } else if (b == 1) {
    // H3[i] = mean(tf[0..i]) (uniform causal softmax; see R1 derivation)
    int h = t & 63, g = t >> 6;
    float vals[32];
    float run = 0.f;
#pragma unroll
    for (int r = 0; r < 32; ++r) { run += tf[(g * 32 + r) * 64 + h]; vals[r] = run; }
    segsum[g][h] = run;
    __syncthreads();
    float off = 0.f;
    for (int gg = 0; gg < g; ++gg) off += segsum[gg][h];
#pragma unroll
    for (int r = 0; r < 32; ++r) {
      int i = g * 32 + r;
      H3[i * 64 + h] = (vals[r] + off) / (float)(i + 1);
    }
  } else {
    int h = t & 63, g = t >> 6;
    float s = 0.f;
    for (int r = 0; r < 32; ++r) s += cf4[(g * 32 + r) * 64 + h];
    A[g * 64 + h] = s;
    __syncthreads();
    for (int p = 8; p; p >>= 1) { if (g < p) A[g * 64 + h] += A[(g + p) * 64 + h]; __syncthreads(); }
    if (t < 64) h4vec[t] = A[t];
  }
}

// ---------------- layernorm + elu ----------------
__global__ void ln_elu_kernel(const float* __restrict__ X, const float* __restrict__ g,
                              const float* __restrict__ b, float* __restrict__ out) {
  __shared__ float red[256];
  int i = blockIdx.x, tid = threadIdx.x;
  float x = X[i * 256 + tid];
  red[tid] = x; __syncthreads();
  for (int s = 128; s; s >>= 1) { if (tid < s) red[tid] += red[tid + s]; __syncthreads(); }
  float mu = red[0] * (1.f / 256.f);
  __syncthreads();
  float d = x - mu;
  red[tid] = d * d; __syncthreads();
  for (int s = 128; s; s >>= 1) { if (tid < s) red[tid] += red[tid + s]; __syncthreads(); }
  float var = red[0] * (1.f / 256.f);
  float y = d / sqrtf(var + EPSV) * g[tid] + b[tid];
  out[i * 256 + tid] = (y > 0.f) ? y : (expf(y) - 1.f);
}

static GD mkgd(const float* A, const float* A2, const float* A3, const float* A4,
               const int* I, const float* B, const float* bias, float* C,
               int M, int K, int Nn, int mode, int act) {
  GD g{A, A2, A3, A4, I, B, bias, C, M, K, Nn, mode, act};
  return g;
}

extern "C" void kernel_launch(void* const* d_in, const int* in_sizes, int n_in,
                              void* d_out, int out_size, void* d_ws, size_t ws_size,
                              hipStream_t stream) {
  const float* V      = (const float*)d_in[0];
  const int*   adj    = (const int*)  d_in[1];
  const float* ph     = (const float*)d_in[2];
  const float* W1     = (const float*)d_in[3];
  // d_in[4] = a_std0: cancels in row softmax — unused
  const float* a_std1 = (const float*)d_in[5];
  const float* ce_w1  = (const float*)d_in[6];
  const float* ce_b1  = (const float*)d_in[7];
  const float* ce_w2  = (const float*)d_in[8];
  const float* ce_b2  = (const float*)d_in[9];
  const float* a_c0   = (const float*)d_in[10];
  const float* a_c1   = (const float*)d_in[11];
  const float* te_w1  = (const float*)d_in[12];
  const float* te_b1  = (const float*)d_in[13];
  const float* te_w2  = (const float*)d_in[14];
  const float* te_b2  = (const float*)d_in[15];
  // d_in[16..17] = a_t0,a_t1: dead (uniform causal softmax)
  const float* co_w1  = (const float*)d_in[18];
  const float* co_b1  = (const float*)d_in[19];
  const float* co_w2  = (const float*)d_in[20];
  const float* co_b2  = (const float*)d_in[21];
  // d_in[22..23] = a_co0,a_co1: size-1 softmax == 1 — unused
  const float* W2     = (const float*)d_in[24];
  const float* Wo     = (const float*)d_in[25];
  const float* bo     = (const float*)d_in[26];
  const float* ln_g   = (const float*)d_in[27];
  const float* ln_b   = (const float*)d_in[28];
  float* out = (float*)d_out;

  float* ws = (float*)d_ws;
  size_t off = 0;
  auto alloc = [&](size_t n) { float* p = ws + off; off += (n + 15) & ~(size_t)15; return p; };

  float* Wh1    = alloc(512 * 256);
  float* Pb     = alloc(512 * 256);
  float* Qb     = alloc(512 * 256);
  float* tfh    = alloc(512 * 256);
  float* cf4h   = alloc(512 * 256);
  float* H1     = alloc(512 * 256);
  float* Wfused = alloc(385 * 256);
  float* T2     = alloc(512 * 256);
  float* tf     = alloc(512 * 64);
  float* cf4    = alloc(512 * 64);
  float* H3     = alloc(512 * 64);
  float* spart  = alloc(1024 * 64);
  float* mpart  = alloc(1024);
  float* dpart  = alloc(1024);
  float* expwsc = alloc(512);
  float* H2row  = alloc(64);
  float* h4vec  = alloc(64);
  (void)ws_size; (void)in_sizes; (void)n_in; (void)out_size;

  // ---- launch 1: six leading GEMMs + wsc slice (z=6: exp(V@(W1@a_std1))) ----
  GD7 sA;
  sA.d[0] = mkgd(V, 0, 0, 0, 0, W1, 0, Wh1, 512, 256, 256, 0, 0);
  sA.d[1] = mkgd(V, 0, 0, 0, 0, ce_w1, 0, Pb, 512, 256, 256, 0, 0);
  sA.d[2] = mkgd(V, 0, 0, 0, 0, ce_w1 + 256 * 256, 0, Qb, 512, 256, 256, 0, 0);
  sA.d[3] = mkgd(V, ph, 0, 0, 0, te_w1, te_b1, tfh, 512, 512, 256, 1, 1);
  sA.d[4] = mkgd(V, 0, 0, 0, adj, co_w1, co_b1, cf4h, 512, 768, 256, 2, 1);
  sA.d[5] = mkgd(W2, 0, 0, 0, 0, Wo, 0, Wfused, 385, 256, 256, 0, 0);
  sA.d[6] = mkgd(W1, a_std1, V, 0, 0, 0, 0, expwsc, 512, 256, 1, 6, 0);
  gemm7_k<<<dim3(4, 16, 7), 256, 0, stream>>>(sA);

  // ---- launch 2: H1 gemm + two N=64 gemms + 1024 pair tiles ----
  MegaArgs ma;
  ma.P = Pb; ma.Q = Qb; ma.b1 = ce_b1; ma.ce_w2 = ce_w2;
  ma.a_c0 = a_c0; ma.a_c1 = a_c1;
  ma.mpart = mpart; ma.dpart = dpart; ma.spart = spart;
  ma.gH1 = mkgd(0, expwsc, 0, 0, adj, Wh1, 0, H1, 512, 512, 256, 4, 0);
  ma.gTf = mkgd(tfh, 0, 0, 0, 0, te_w2, te_b2, tf, 512, 256, 64, 0, 0);
  ma.gCf = mkgd(cf4h, 0, 0, 0, 0, co_w2, co_b2, cf4, 512, 256, 64, 0, 0);
  mega_k<<<1120, 256, 0, stream>>>(ma);

  // ---- launch 3: H2 finalize + h3 prefix mean + colsum ----
  mini_k<<<3, 1024, 0, stream>>>(mpart, dpart, spart, ce_b2, H2row, tf, H3, cf4, h4vec);

  // ---- launch 4: T2 = virtual-Hc @ Wfused + bo ----
  GD gF = mkgd(H1, H2row, H3, h4vec, 0, Wfused, bo, T2, 512, 385, 256, 3, 0);
  gemm1_k<<<dim3(4, 16), 256, 0, stream>>>(gF);

  // ---- launch 5: layernorm + elu ----
  ln_elu_kernel<<<512, 256, 0, stream>>>(T2, ln_g, ln_b, out);
}